// Round 15
// baseline (579.553 us; speedup 1.0000x reference)
//
#include <hip/hip_runtime.h>
#include <hip/hip_bf16.h>

// GAT 3-layer: N=50000 nodes, E=800000 edges, H=6 heads.
// R1-R10: tiled/MFMA-split-bf16 GEMMs (operands pre-packed in fragment layout),
//         CSR dst-centric fused softmax+aggregate, bf16 h. absmax=0.
// R11: pool-fused aggregate regressed (block barrier after variable-trip gather).
// R12: barrier-free aggregate, bf16 layer-3 out + bf16 pool (560us best).
// R13: per-(node,head) agg spilled (acc[64] @ VGPR52) + 8x fewer threads: 920us.
// R14: c16 2-pass agg: VALU 76->43% but SAME 117us -> aggregate is bound by the
//      L2-miss gather path (~315MB @ 2.7TB/s), not VALU.
// R15: leaky_relu is monotone => row-max = leaky(max es + ed): tiny per-(node,
//      head) rowmax kernel (es-only, L2-resident), aggregates become single-pass
//      (no pass-1 rescan, no online rescale). C8 for L1/L2, C16 for L3.

#define HHEADS 6

typedef __attribute__((ext_vector_type(8))) short bf16x8;   // 8 bf16 = 4 VGPR
typedef __attribute__((ext_vector_type(4))) float f32x4;    // mfma C/D

__device__ __forceinline__ float bfl(unsigned u) { return __uint_as_float(u << 16); }
__device__ __forceinline__ float bfh(unsigned u) { return __uint_as_float(u & 0xffff0000u); }
__device__ __forceinline__ unsigned short f2bf(float v) {  // RNE f32->bf16
    unsigned u = __float_as_uint(v);
    return (unsigned short)((u + 0x7fffu + ((u >> 16) & 1u)) >> 16);
}
__device__ __forceinline__ float bf2f(unsigned short h) {
    return __uint_as_float((unsigned)h << 16);
}

// ---------------- CSR build ----------------
__global__ void hist_kernel(const int* __restrict__ dst, int* __restrict__ count, int E) {
    int e = blockIdx.x * blockDim.x + threadIdx.x;
    if (e >= E) return;
    atomicAdd(&count[dst[e]], 1);
}

__global__ void scan_block(const int* __restrict__ count, int* __restrict__ offsets,
                           int* __restrict__ bsum, int n) {
    __shared__ int s[1024];
    int i = blockIdx.x * 1024 + threadIdx.x;
    int v = (i < n) ? count[i] : 0;
    s[threadIdx.x] = v;
    __syncthreads();
    for (int off = 1; off < 1024; off <<= 1) {
        int t = (threadIdx.x >= (unsigned)off) ? s[threadIdx.x - off] : 0;
        __syncthreads();
        s[threadIdx.x] += t;
        __syncthreads();
    }
    if (i < n) offsets[i] = s[threadIdx.x] - v;
    if (threadIdx.x == 1023) bsum[blockIdx.x] = s[1023];
}

__global__ void scan_tops(int* __restrict__ bsum, int nb) {
    __shared__ int s[64];
    int t = threadIdx.x;
    int v = (t < nb) ? bsum[t] : 0;
    s[t] = v;
    __syncthreads();
    for (int off = 1; off < 64; off <<= 1) {
        int tmp = (t >= off) ? s[t - off] : 0;
        __syncthreads();
        s[t] += tmp;
        __syncthreads();
    }
    if (t < nb) bsum[t] = s[t] - v;
}

__global__ void scan_add(int* __restrict__ offsets, const int* __restrict__ bsum, int n,
                         int total) {
    int i = blockIdx.x * 1024 + threadIdx.x;
    if (i < n) offsets[i] += bsum[blockIdx.x];
    if (i == 0) offsets[n] = total;
}

__global__ void scatter_kernel(const int* __restrict__ src, const int* __restrict__ dst,
                               const int* __restrict__ offsets, int* __restrict__ cursor,
                               int* __restrict__ ssrc, int E) {
    int e = blockIdx.x * blockDim.x + threadIdx.x;
    if (e >= E) return;
    int d = dst[e];
    int pos = offsets[d] + atomicAdd(&cursor[d], 1);
    ssrc[pos] = src[e];
}

// ---------------- weight repacks ----------------
__global__ void repack_w(const float* __restrict__ W, float* __restrict__ Wp, int FIN, int F) {
    int HF = HHEADS * F;
    int i = blockIdx.x * blockDim.x + threadIdx.x;
    if (i >= FIN * HF) return;
    int k = i / HF, c = i % HF;
    int hd = c / F, f = c % F;
    Wp[i] = W[(hd * FIN + k) * F + f];
}

// split-bf16 pack in MFMA B-fragment layout (B^T: lane n=..&15, k contiguous)
__global__ void repack_w_mfma(const float* __restrict__ W, unsigned short* __restrict__ bh,
                              unsigned short* __restrict__ bl, int FIN, int F, int NPAD) {
    int i = blockIdx.x * blockDim.x + threadIdx.x;
    if (i >= FIN * NPAD) return;
    int k = i / NPAD, n = i % NPAD;
    int NKT = FIN / 32;
    int HF = HHEADS * F;
    float w = 0.f;
    if (n < HF) {
        int hd = n / F, f = n % F;
        w = W[(hd * FIN + k) * F + f];
    }
    unsigned short h = f2bf(w);
    unsigned short l = f2bf(w - bf2f(h));
    size_t e = ((size_t)((n >> 4) * NKT + (k >> 5)) * 64 + ((n & 15) | (((k >> 3) & 3) << 4))) * 8 +
               (k & 7);
    bh[e] = h;
    bl[e] = l;
}

// ---------------- small GEMM + fused attn (layer 1, K=11, F=16) ----------------
template <int BM, int BN, int BK>
__global__ __launch_bounds__(256) void gemm_small_attn(const float* __restrict__ A,
                                                       const float* __restrict__ B,
                                                       __hip_bfloat16* __restrict__ C,
                                                       const float* __restrict__ as_,
                                                       const float* __restrict__ ad_,
                                                       float* __restrict__ es,
                                                       float* __restrict__ ed, int M, int K,
                                                       int N) {
    __shared__ float As[BK][BM + 4];
    __shared__ float Bs[BK][BN];
    int tid = threadIdx.x;
    int tx = tid % 16, ty = tid / 16;
    int m0 = blockIdx.y * BM, n0 = blockIdx.x * BN;
    float acc[4][4] = {};
    for (int kk0 = 0; kk0 < K; kk0 += BK) {
#pragma unroll
        for (int i = 0; i < (BM * BK) / 256; ++i) {
            int idx = tid + i * 256;
            int m = idx / BK, k = idx % BK;
            float v = 0.f;
            if (m0 + m < M && kk0 + k < K) v = A[(size_t)(m0 + m) * K + kk0 + k];
            As[k][m] = v;
        }
#pragma unroll
        for (int i = 0; i < (BK * BN) / 1024; ++i) {
            int idx = tid + i * 256;
            int k = idx / (BN / 4), n4 = idx % (BN / 4);
            float4 v = make_float4(0.f, 0.f, 0.f, 0.f);
            if (kk0 + k < K && n0 + n4 * 4 < N)
                v = *(const float4*)&B[(size_t)(kk0 + k) * N + n0 + n4 * 4];
            *(float4*)&Bs[k][n4 * 4] = v;
        }
        __syncthreads();
#pragma unroll
        for (int k = 0; k < BK; ++k) {
            float4 av = *(const float4*)&As[k][ty * 4];
            float4 bv = *(const float4*)&Bs[k][tx * 4];
            float a[4] = {av.x, av.y, av.z, av.w};
            float b[4] = {bv.x, bv.y, bv.z, bv.w};
#pragma unroll
            for (int i = 0; i < 4; ++i)
#pragma unroll
                for (int j = 0; j < 4; ++j) acc[i][j] += a[i] * b[j];
        }
        __syncthreads();
    }
    bool colok = (n0 + tx * 4) < N;
    float asv[4], adv[4];
#pragma unroll
    for (int j = 0; j < 4; ++j) {
        int col = n0 + tx * 4 + j;
        asv[j] = (col < N) ? as_[col] : 0.f;
        adv[j] = (col < N) ? ad_[col] : 0.f;
    }
#pragma unroll
    for (int i = 0; i < 4; ++i) {
        int m = m0 + ty * 4 + i;
        bool mok = m < M;
        if (mok && colok) {
            __hip_bfloat16 tmp[4];
#pragma unroll
            for (int j = 0; j < 4; ++j) tmp[j] = __float2bfloat16(acc[i][j]);
            *(uint2*)&C[(size_t)m * N + n0 + tx * 4] = *(uint2*)tmp;
        }
        float ps = 0.f, pd = 0.f;
#pragma unroll
        for (int j = 0; j < 4; ++j) {
            ps += acc[i][j] * asv[j];
            pd += acc[i][j] * adv[j];
        }
        ps += __shfl_down(ps, 2, 4);
        ps += __shfl_down(ps, 1, 4);
        pd += __shfl_down(pd, 2, 4);
        pd += __shfl_down(pd, 1, 4);
        if (mok && colok && (tx & 3) == 0) {
            int hd = (n0 + tx * 4) >> 4;  // F=16
            es[(size_t)m * HHEADS + hd] = ps;
            ed[(size_t)m * HHEADS + hd] = pd;
        }
    }
}

// ---------------- MFMA split-bf16 GEMM + fused attn (layers 2/3) ----------------
template <int K, int NREAL, int NPAD, int F>
__global__ __launch_bounds__(256) void gemm_attn_mfma(
    const unsigned short* __restrict__ Ah, const unsigned short* __restrict__ Al,
    const unsigned short* __restrict__ Bh, const unsigned short* __restrict__ Bl,
    __hip_bfloat16* __restrict__ C, const float* __restrict__ as_,
    const float* __restrict__ ad_, float* __restrict__ es, float* __restrict__ ed, int M) {
    constexpr int NKT = K / 32;
    __shared__ unsigned short sAh[4096], sAl[4096], sBh[4096], sBl[4096];
    int tid = threadIdx.x;
    int lane = tid & 63, wave = tid >> 6;
    int wrow = wave >> 1, wcol = wave & 1;
    int quad = lane >> 4, c16 = lane & 15;
    int m0 = blockIdx.y * 128, n0 = blockIdx.x * 128;
    int bt16 = m0 >> 4, bn16 = n0 >> 4;

    f32x4 acc[4][4] = {};
    for (int kt = 0; kt < NKT; ++kt) {
#pragma unroll
        for (int rep = 0; rep < 2; ++rep) {
            int chunk = tid + rep * 256;
            int tile = chunk >> 6, e8 = chunk & 63;
            size_t aoff = ((size_t)((bt16 + tile) * NKT + kt) * 64 + e8) * 8;
            size_t boff = ((size_t)((bn16 + tile) * NKT + kt) * 64 + e8) * 8;
            *(uint4*)&sAh[chunk * 8] = *(const uint4*)&Ah[aoff];
            *(uint4*)&sAl[chunk * 8] = *(const uint4*)&Al[aoff];
            *(uint4*)&sBh[chunk * 8] = *(const uint4*)&Bh[boff];
            *(uint4*)&sBl[chunk * 8] = *(const uint4*)&Bl[boff];
        }
        __syncthreads();
        bf16x8 fah[4], fal[4], fbh[4], fbl[4];
#pragma unroll
        for (int i = 0; i < 4; ++i) {
            fah[i] = *(const bf16x8*)&sAh[(wrow * 4 + i) * 512 + lane * 8];
            fal[i] = *(const bf16x8*)&sAl[(wrow * 4 + i) * 512 + lane * 8];
            fbh[i] = *(const bf16x8*)&sBh[(wcol * 4 + i) * 512 + lane * 8];
            fbl[i] = *(const bf16x8*)&sBl[(wcol * 4 + i) * 512 + lane * 8];
        }
#pragma unroll
        for (int i = 0; i < 4; ++i)
#pragma unroll
            for (int j = 0; j < 4; ++j) {
                acc[i][j] = __builtin_amdgcn_mfma_f32_16x16x32_bf16(fah[i], fbh[j], acc[i][j],
                                                                    0, 0, 0);
                acc[i][j] = __builtin_amdgcn_mfma_f32_16x16x32_bf16(fal[i], fbh[j], acc[i][j],
                                                                    0, 0, 0);
                acc[i][j] = __builtin_amdgcn_mfma_f32_16x16x32_bf16(fah[i], fbl[j], acc[i][j],
                                                                    0, 0, 0);
            }
        __syncthreads();
    }

    float asv[4], adv[4];
#pragma unroll
    for (int j = 0; j < 4; ++j) {
        int col = n0 + wcol * 64 + j * 16 + c16;
        bool ok = col < NREAL;
        asv[j] = ok ? as_[col] : 0.f;
        adv[j] = ok ? ad_[col] : 0.f;
    }
#pragma unroll
    for (int i = 0; i < 4; ++i) {
#pragma unroll
        for (int r = 0; r < 4; ++r) {
            int m = m0 + wrow * 64 + i * 16 + quad * 4 + r;
            bool mok = m < M;
            if (mok) {
#pragma unroll
                for (int j = 0; j < 4; ++j) {
                    int col = n0 + wcol * 64 + j * 16 + c16;
                    if (col < NREAL) C[(size_t)m * NREAL + col] = __float2bfloat16(acc[i][j][r]);
                }
            }
            if (F == 64) {
                float ps = acc[i][0][r] * asv[0] + acc[i][1][r] * asv[1] +
                           acc[i][2][r] * asv[2] + acc[i][3][r] * asv[3];
                float pd = acc[i][0][r] * adv[0] + acc[i][1][r] * adv[1] +
                           acc[i][2][r] * adv[2] + acc[i][3][r] * adv[3];
#pragma unroll
                for (int off = 8; off > 0; off >>= 1) {
                    ps += __shfl_down(ps, off, 16);
                    pd += __shfl_down(pd, off, 16);
                }
                if (mok && c16 == 0) {
                    int hd = (n0 + wcol * 64) / 64;
                    es[(size_t)m * HHEADS + hd] = ps;
                    ed[(size_t)m * HHEADS + hd] = pd;
                }
            } else {  // F == 32: two heads per wave-column
                float psA = acc[i][0][r] * asv[0] + acc[i][1][r] * asv[1];
                float pdA = acc[i][0][r] * adv[0] + acc[i][1][r] * adv[1];
                float psB = acc[i][2][r] * asv[2] + acc[i][3][r] * asv[3];
                float pdB = acc[i][2][r] * adv[2] + acc[i][3][r] * adv[3];
#pragma unroll
                for (int off = 8; off > 0; off >>= 1) {
                    psA += __shfl_down(psA, off, 16);
                    pdA += __shfl_down(pdA, off, 16);
                    psB += __shfl_down(psB, off, 16);
                    pdB += __shfl_down(pdB, off, 16);
                }
                if (mok && c16 == 0) {
                    int colbase = n0 + wcol * 64;
                    if (colbase < NREAL) {
                        int hd = colbase / 32;
                        es[(size_t)m * HHEADS + hd] = psA;
                        ed[(size_t)m * HHEADS + hd] = pdA;
                        es[(size_t)m * HHEADS + hd + 1] = psB;
                        ed[(size_t)m * HHEADS + hd + 1] = pdB;
                    }
                }
            }
        }
    }
}

// ---------------- row max (leaky_relu is monotone) ----------------
// m[node,hd] = leaky(max_j es[src_j,hd] + ed[node,hd]); es gathers L2-resident.
__global__ void rowmax_kernel(const float* __restrict__ es, const float* __restrict__ ed,
                              const int* __restrict__ offsets, const int* __restrict__ ssrc,
                              float* __restrict__ mrow, int n) {
    int i = blockIdx.x * blockDim.x + threadIdx.x;
    if (i >= n * HHEADS) return;
    int node = i / HHEADS, hd = i % HHEADS;
    int a = offsets[node], b = offsets[node + 1];
    float mx = -1e30f;
    for (int j = a; j < b; ++j) mx = fmaxf(mx, es[ssrc[j] * HHEADS + hd]);
    float v = mx + ed[i];
    mrow[i] = v > 0.f ? v : 0.2f * v;
}

// ---------------- single-pass softmax-aggregate ----------------
// Thread owns CH channels (CH*8 <= 16 f32 acc, no spill). Row max precomputed
// (rowmax_kernel) -> single gather pass: w=exp(v-m), acc+=w*h, l+=w.
// No block barrier (R11 lesson). PACK: split-bf16 MFMA A-operand planes.
template <int F, int CH, bool PACK>
__global__ __launch_bounds__(256) void aggregate_sp(
    const __hip_bfloat16* __restrict__ h, const float* __restrict__ es,
    const float* __restrict__ ed, const float* __restrict__ mrow,
    const int* __restrict__ offsets, const int* __restrict__ ssrc,
    unsigned short* __restrict__ oh, unsigned short* __restrict__ ol,
    __hip_bfloat16* __restrict__ outb, int n) {
    constexpr int HF = HHEADS * F;
    constexpr int NQ = HF / CH;
    int tid = blockIdx.x * blockDim.x + threadIdx.x;
    if (tid >= n * NQ) return;
    int node = tid / NQ, q = tid % NQ;
    int c = q * CH, hd = c / F;
    int a = offsets[node], b = offsets[node + 1];
    float edv = ed[node * HHEADS + hd];
    float m = mrow[node * HHEADS + hd];
    float l = 0.f;
    float acc[CH] = {};
    const unsigned short* hbase = (const unsigned short*)h + c;
    for (int j = a; j < b; ++j) {
        int s = ssrc[j];
        float v = es[s * HHEADS + hd] + edv;
        v = v > 0.f ? v : 0.2f * v;  // leaky relu 0.2
        float wgt = expf(v - m);
        l += wgt;
        const unsigned short* hp = hbase + (size_t)s * HF;
#pragma unroll
        for (int g2 = 0; g2 < CH / 8; ++g2) {
            uint4 hv = *(const uint4*)(hp + g2 * 8);
            acc[g2 * 8 + 0] += wgt * bfl(hv.x);
            acc[g2 * 8 + 1] += wgt * bfh(hv.x);
            acc[g2 * 8 + 2] += wgt * bfl(hv.y);
            acc[g2 * 8 + 3] += wgt * bfh(hv.y);
            acc[g2 * 8 + 4] += wgt * bfl(hv.z);
            acc[g2 * 8 + 5] += wgt * bfh(hv.z);
            acc[g2 * 8 + 6] += wgt * bfl(hv.w);
            acc[g2 * 8 + 7] += wgt * bfh(hv.w);
        }
    }
    float invd = 1.0f / (l + 1e-16f);
#pragma unroll
    for (int g2 = 0; g2 < CH / 8; ++g2) {
        float res[8];
#pragma unroll
        for (int k = 0; k < 8; ++k) {
            float v = acc[g2 * 8 + k] * invd;
            res[k] = v > 0.f ? v : (expf(v) - 1.0f);  // elu
        }
        int cc = c + g2 * 8;
        if (PACK) {
            constexpr int NKT = HF / 32;
            unsigned short th[8], tl[8];
#pragma unroll
            for (int k = 0; k < 8; ++k) {
                unsigned short hh = f2bf(res[k]);
                th[k] = hh;
                tl[k] = f2bf(res[k] - bf2f(hh));
            }
            int lq = (node & 15) | (((cc >> 3) & 3) << 4);
            size_t base = ((size_t)((node >> 4) * NKT + (cc >> 5)) * 64 + lq) * 8;
            *(uint4*)&oh[base] = *(uint4*)th;
            *(uint4*)&ol[base] = *(uint4*)tl;
        } else {
            __hip_bfloat16 tb[8];
#pragma unroll
            for (int k = 0; k < 8; ++k) tb[k] = __float2bfloat16(res[k]);
            *(uint4*)&outb[(size_t)node * HF + cc] = *(uint4*)tb;
        }
    }
}

// ---------------- pooling (bf16 input) + head ----------------
__global__ void pool_kernel(const __hip_bfloat16* __restrict__ out3, float* __restrict__ g,
                            int n) {
    int b = blockIdx.x, t = threadIdx.x;  // blockDim = 192
    int chunk = (n + gridDim.x - 1) / gridDim.x;
    int n0 = b * chunk, n1 = min(n, n0 + chunk);
    float a0 = 0.f, a1 = 0.f;
    const unsigned* p = (const unsigned*)out3;
    for (int node = n0; node < n1; ++node) {
        unsigned u = p[(size_t)node * 192 + t];
        a0 += bfl(u);
        a1 += bfh(u);
    }
    atomicAdd(&g[2 * t], a0);
    atomicAdd(&g[2 * t + 1], a1);
}

__global__ void final_kernel(const float* __restrict__ g, const float* __restrict__ Wd,
                             const float* __restrict__ bd, float* __restrict__ outp) {
    __shared__ float red[384];
    int t = threadIdx.x;  // blockDim = 384
    float v = g[t];
    red[t] = v * v;
    __syncthreads();
    for (int s = 192; s >= 3; s >>= 1) {
        if (t < s) red[t] += red[t + s];
        __syncthreads();
    }
    __shared__ float scale_s;
    if (t == 0) {
        float norm = sqrtf(red[0] + red[1] + red[2]);
        scale_s = 1.0f / fmaxf(norm, 1e-12f);
    }
    __syncthreads();
    float scale = scale_s;
    red[t] = v * scale * Wd[t];
    __syncthreads();
    for (int s = 192; s >= 3; s >>= 1) {
        if (t < s) red[t] += red[t + s];
        __syncthreads();
    }
    if (t == 0) outp[0] = red[0] + red[1] + red[2] + bd[0];
}

// ---------------- host side ----------------
extern "C" void kernel_launch(void* const* d_in, const int* in_sizes, int n_in, void* d_out,
                              int out_size, void* d_ws, size_t ws_size, hipStream_t stream) {
    const float* x = (const float*)d_in[0];
    const int* ei = (const int*)d_in[1];
    const float* W1 = (const float*)d_in[2];
    const float* a1s = (const float*)d_in[3];
    const float* a1d = (const float*)d_in[4];
    const float* W2 = (const float*)d_in[5];
    const float* a2s = (const float*)d_in[6];
    const float* a2d = (const float*)d_in[7];
    const float* W3 = (const float*)d_in[8];
    const float* a3s = (const float*)d_in[9];
    const float* a3d = (const float*)d_in[10];
    const float* Wd = (const float*)d_in[11];
    const float* bd = (const float*)d_in[12];
    float* outp = (float*)d_out;

    const int N = in_sizes[0] / 11;
    const int E = in_sizes[1] / 2;
    const int* src = ei;
    const int* dst = ei + E;

    const int NT16 = ((N + 127) / 128) * 8;  // padded 16-row tiles

    char* w = (char*)d_ws;
    size_t off = 0;
    auto A = [&](size_t bytes) {
        size_t o = off;
        off += (bytes + 255) & ~(size_t)255;
        return o;
    };
    __hip_bfloat16* bufH = (__hip_bfloat16*)(w + A((size_t)N * 384 * 2));  // h (bf16)
    __hip_bfloat16* bufO = (__hip_bfloat16*)(w + A((size_t)N * 384 * 2));  // layer3 out (bf16)
    unsigned short* apH = (unsigned short*)(w + A((size_t)NT16 * 6 * 512 * 2));  // A-pack hi
    unsigned short* apL = (unsigned short*)(w + A((size_t)NT16 * 6 * 512 * 2));  // A-pack lo
    unsigned short* b2H = (unsigned short*)(w + A((size_t)16 * 3 * 512 * 2));    // W2 pack
    unsigned short* b2L = (unsigned short*)(w + A((size_t)16 * 3 * 512 * 2));
    unsigned short* b3H = (unsigned short*)(w + A((size_t)24 * 6 * 512 * 2));    // W3 pack
    unsigned short* b3L = (unsigned short*)(w + A((size_t)24 * 6 * 512 * 2));
    float* es = (float*)(w + A((size_t)N * HHEADS * 4));
    float* ed = (float*)(w + A((size_t)N * HHEADS * 4));
    float* mrow = (float*)(w + A((size_t)N * HHEADS * 4));
    float* wp = (float*)(w + A((size_t)11 * 96 * 4));  // layer-1 f32 repack
    int* count = (int*)(w + A((size_t)(N + 1) * 4));
    int* cursor = (int*)(w + A((size_t)(N + 1) * 4));
    int* offsets = (int*)(w + A((size_t)(N + 1) * 4));
    int* bsum = (int*)(w + A(64 * 4));
    int* ssrc = (int*)(w + A((size_t)E * 4));
    float* g = (float*)(w + A(384 * 4));

    // CSR build (by dst)
    hipMemsetAsync(count, 0, (size_t)N * 4, stream);
    hipMemsetAsync(cursor, 0, (size_t)N * 4, stream);
    hipMemsetAsync(g, 0, 384 * 4, stream);
    hist_kernel<<<(E + 255) / 256, 256, 0, stream>>>(dst, count, E);
    int nb = (N + 1023) / 1024;
    scan_block<<<nb, 1024, 0, stream>>>(count, offsets, bsum, N);
    scan_tops<<<1, 64, 0, stream>>>(bsum, nb);
    scan_add<<<nb, 1024, 0, stream>>>(offsets, bsum, N, E);
    scatter_kernel<<<(E + 255) / 256, 256, 0, stream>>>(src, dst, offsets, cursor, ssrc, E);

    // weight packs
    repack_w<<<(11 * 96 + 255) / 256, 256, 0, stream>>>(W1, wp, 11, 16);
    repack_w_mfma<<<(96 * 256 + 255) / 256, 256, 0, stream>>>(W2, b2H, b2L, 96, 32, 256);
    repack_w_mfma<<<(192 * 384 + 255) / 256, 256, 0, stream>>>(W3, b3H, b3L, 192, 64, 384);

    // zero A-pack pad tiles for both layouts (NKT=3 and 6)
    const int t16v = N / 16;
    const int padT = NT16 - t16v;
    hipMemsetAsync(apH + (size_t)t16v * 3 * 512, 0, (size_t)padT * 3 * 512 * 2, stream);
    hipMemsetAsync(apL + (size_t)t16v * 3 * 512, 0, (size_t)padT * 3 * 512 * 2, stream);
    hipMemsetAsync(apH + (size_t)t16v * 6 * 512, 0, (size_t)padT * 6 * 512 * 2, stream);
    hipMemsetAsync(apL + (size_t)t16v * 6 * 512, 0, (size_t)padT * 6 * 512 * 2, stream);

    long htot = (long)N * HHEADS;

    // ---- layer 1 (FIN=11, F=16): gemm + fused attn terms ----
    {
        dim3 grid((96 + 63) / 64, (N + 63) / 64);
        gemm_small_attn<64, 64, 32><<<grid, 256, 0, stream>>>(x, wp, bufH, a1s, a1d, es, ed, N,
                                                              11, 96);
    }
    rowmax_kernel<<<(htot + 255) / 256, 256, 0, stream>>>(es, ed, offsets, ssrc, mrow, N);
    {
        long total = (long)N * (96 / 8);
        aggregate_sp<16, 8, true><<<(total + 255) / 256, 256, 0, stream>>>(
            bufH, es, ed, mrow, offsets, ssrc, apH, apL, nullptr, N);
    }

    // ---- layer 2 (K=96, N=192 pad 256, F=32) ----
    {
        dim3 grid(256 / 128, (N + 127) / 128);
        gemm_attn_mfma<96, 192, 256, 32><<<grid, 256, 0, stream>>>(apH, apL, b2H, b2L, bufH,
                                                                   a2s, a2d, es, ed, N);
    }
    rowmax_kernel<<<(htot + 255) / 256, 256, 0, stream>>>(es, ed, offsets, ssrc, mrow, N);
    {
        long total = (long)N * (192 / 8);
        aggregate_sp<32, 8, true><<<(total + 255) / 256, 256, 0, stream>>>(
            bufH, es, ed, mrow, offsets, ssrc, apH, apL, nullptr, N);
    }

    // ---- layer 3 (K=192, N=384, F=64) ----
    {
        dim3 grid(384 / 128, (N + 127) / 128);
        gemm_attn_mfma<192, 384, 384, 64><<<grid, 256, 0, stream>>>(apH, apL, b3H, b3L, bufH,
                                                                    a3s, a3d, es, ed, N);
    }
    rowmax_kernel<<<(htot + 255) / 256, 256, 0, stream>>>(es, ed, offsets, ssrc, mrow, N);
    {
        long total = (long)N * (384 / 16);
        aggregate_sp<64, 16, false><<<(total + 255) / 256, 256, 0, stream>>>(
            bufH, es, ed, mrow, offsets, ssrc, nullptr, nullptr, bufO, N);
    }

    // sum-pool (bf16 in) -> normalize -> dense
    pool_kernel<<<256, 192, 0, stream>>>(bufO, g, N);
    final_kernel<<<1, 384, 0, stream>>>(g, Wd, bd, outp);
}

// Round 16
// 573.255 us; speedup vs baseline: 1.0110x; 1.0110x over previous
//
#include <hip/hip_runtime.h>
#include <hip/hip_bf16.h>

// GAT 3-layer: N=50000 nodes, E=800000 edges, H=6 heads.
// R1-R10: tiled/MFMA-split-bf16 GEMMs (operands pre-packed in fragment layout),
//         CSR dst-centric fused softmax+aggregate, bf16 h. absmax=0.
// R11: pool-fused aggregate regressed (block barrier after variable-trip gather).
// R12: barrier-free aggregate, bf16 layer-3 out + bf16 pool (560us).
// R13: per-(node,head) agg spilled + too few threads: 920us.
// R14: 2-pass agg: VALU 76->43% but SAME time -> gather-path bound.
// R15: single-pass agg via rowmax kernel: L3 agg 117->102us, but 3 rowmax
//      gather kernels (+40us) ate the gain (579 total).
// R16: rowmax -> per-head GLOBAL es max (softmax shift only needs an upper
//      bound; leaky monotone => leaky(gmax+ed) >= every row logit). One 2us
//      sequential reduction per layer, shift computed inline. No row gathers.

#define HHEADS 6

typedef __attribute__((ext_vector_type(8))) short bf16x8;   // 8 bf16 = 4 VGPR
typedef __attribute__((ext_vector_type(4))) float f32x4;    // mfma C/D

__device__ __forceinline__ float bfl(unsigned u) { return __uint_as_float(u << 16); }
__device__ __forceinline__ float bfh(unsigned u) { return __uint_as_float(u & 0xffff0000u); }
__device__ __forceinline__ unsigned short f2bf(float v) {  // RNE f32->bf16
    unsigned u = __float_as_uint(v);
    return (unsigned short)((u + 0x7fffu + ((u >> 16) & 1u)) >> 16);
}
__device__ __forceinline__ float bf2f(unsigned short h) {
    return __uint_as_float((unsigned)h << 16);
}
// monotone float<->uint for atomicMax on floats (all fkeys > 0, memset-0 = -inf)
__device__ __forceinline__ unsigned fkey(float f) {
    unsigned u = __float_as_uint(f);
    return (u >> 31) ? ~u : (u | 0x80000000u);
}
__device__ __forceinline__ float funkey(unsigned k) {
    return (k >> 31) ? __uint_as_float(k & 0x7fffffffu) : __uint_as_float(~k);
}

// ---------------- CSR build ----------------
__global__ void hist_kernel(const int* __restrict__ dst, int* __restrict__ count, int E) {
    int e = blockIdx.x * blockDim.x + threadIdx.x;
    if (e >= E) return;
    atomicAdd(&count[dst[e]], 1);
}

__global__ void scan_block(const int* __restrict__ count, int* __restrict__ offsets,
                           int* __restrict__ bsum, int n) {
    __shared__ int s[1024];
    int i = blockIdx.x * 1024 + threadIdx.x;
    int v = (i < n) ? count[i] : 0;
    s[threadIdx.x] = v;
    __syncthreads();
    for (int off = 1; off < 1024; off <<= 1) {
        int t = (threadIdx.x >= (unsigned)off) ? s[threadIdx.x - off] : 0;
        __syncthreads();
        s[threadIdx.x] += t;
        __syncthreads();
    }
    if (i < n) offsets[i] = s[threadIdx.x] - v;
    if (threadIdx.x == 1023) bsum[blockIdx.x] = s[1023];
}

__global__ void scan_tops(int* __restrict__ bsum, int nb) {
    __shared__ int s[64];
    int t = threadIdx.x;
    int v = (t < nb) ? bsum[t] : 0;
    s[t] = v;
    __syncthreads();
    for (int off = 1; off < 64; off <<= 1) {
        int tmp = (t >= off) ? s[t - off] : 0;
        __syncthreads();
        s[t] += tmp;
        __syncthreads();
    }
    if (t < nb) bsum[t] = s[t] - v;
}

__global__ void scan_add(int* __restrict__ offsets, const int* __restrict__ bsum, int n,
                         int total) {
    int i = blockIdx.x * 1024 + threadIdx.x;
    if (i < n) offsets[i] += bsum[blockIdx.x];
    if (i == 0) offsets[n] = total;
}

__global__ void scatter_kernel(const int* __restrict__ src, const int* __restrict__ dst,
                               const int* __restrict__ offsets, int* __restrict__ cursor,
                               int* __restrict__ ssrc, int E) {
    int e = blockIdx.x * blockDim.x + threadIdx.x;
    if (e >= E) return;
    int d = dst[e];
    int pos = offsets[d] + atomicAdd(&cursor[d], 1);
    ssrc[pos] = src[e];
}

// ---------------- weight repacks ----------------
__global__ void repack_w(const float* __restrict__ W, float* __restrict__ Wp, int FIN, int F) {
    int HF = HHEADS * F;
    int i = blockIdx.x * blockDim.x + threadIdx.x;
    if (i >= FIN * HF) return;
    int k = i / HF, c = i % HF;
    int hd = c / F, f = c % F;
    Wp[i] = W[(hd * FIN + k) * F + f];
}

// split-bf16 pack in MFMA B-fragment layout (B^T: lane n=..&15, k contiguous)
__global__ void repack_w_mfma(const float* __restrict__ W, unsigned short* __restrict__ bh,
                              unsigned short* __restrict__ bl, int FIN, int F, int NPAD) {
    int i = blockIdx.x * blockDim.x + threadIdx.x;
    if (i >= FIN * NPAD) return;
    int k = i / NPAD, n = i % NPAD;
    int NKT = FIN / 32;
    int HF = HHEADS * F;
    float w = 0.f;
    if (n < HF) {
        int hd = n / F, f = n % F;
        w = W[(hd * FIN + k) * F + f];
    }
    unsigned short h = f2bf(w);
    unsigned short l = f2bf(w - bf2f(h));
    size_t e = ((size_t)((n >> 4) * NKT + (k >> 5)) * 64 + ((n & 15) | (((k >> 3) & 3) << 4))) * 8 +
               (k & 7);
    bh[e] = h;
    bl[e] = l;
}

// ---------------- small GEMM + fused attn (layer 1, K=11, F=16) ----------------
template <int BM, int BN, int BK>
__global__ __launch_bounds__(256) void gemm_small_attn(const float* __restrict__ A,
                                                       const float* __restrict__ B,
                                                       __hip_bfloat16* __restrict__ C,
                                                       const float* __restrict__ as_,
                                                       const float* __restrict__ ad_,
                                                       float* __restrict__ es,
                                                       float* __restrict__ ed, int M, int K,
                                                       int N) {
    __shared__ float As[BK][BM + 4];
    __shared__ float Bs[BK][BN];
    int tid = threadIdx.x;
    int tx = tid % 16, ty = tid / 16;
    int m0 = blockIdx.y * BM, n0 = blockIdx.x * BN;
    float acc[4][4] = {};
    for (int kk0 = 0; kk0 < K; kk0 += BK) {
#pragma unroll
        for (int i = 0; i < (BM * BK) / 256; ++i) {
            int idx = tid + i * 256;
            int m = idx / BK, k = idx % BK;
            float v = 0.f;
            if (m0 + m < M && kk0 + k < K) v = A[(size_t)(m0 + m) * K + kk0 + k];
            As[k][m] = v;
        }
#pragma unroll
        for (int i = 0; i < (BK * BN) / 1024; ++i) {
            int idx = tid + i * 256;
            int k = idx / (BN / 4), n4 = idx % (BN / 4);
            float4 v = make_float4(0.f, 0.f, 0.f, 0.f);
            if (kk0 + k < K && n0 + n4 * 4 < N)
                v = *(const float4*)&B[(size_t)(kk0 + k) * N + n0 + n4 * 4];
            *(float4*)&Bs[k][n4 * 4] = v;
        }
        __syncthreads();
#pragma unroll
        for (int k = 0; k < BK; ++k) {
            float4 av = *(const float4*)&As[k][ty * 4];
            float4 bv = *(const float4*)&Bs[k][tx * 4];
            float a[4] = {av.x, av.y, av.z, av.w};
            float b[4] = {bv.x, bv.y, bv.z, bv.w};
#pragma unroll
            for (int i = 0; i < 4; ++i)
#pragma unroll
                for (int j = 0; j < 4; ++j) acc[i][j] += a[i] * b[j];
        }
        __syncthreads();
    }
    bool colok = (n0 + tx * 4) < N;
    float asv[4], adv[4];
#pragma unroll
    for (int j = 0; j < 4; ++j) {
        int col = n0 + tx * 4 + j;
        asv[j] = (col < N) ? as_[col] : 0.f;
        adv[j] = (col < N) ? ad_[col] : 0.f;
    }
#pragma unroll
    for (int i = 0; i < 4; ++i) {
        int m = m0 + ty * 4 + i;
        bool mok = m < M;
        if (mok && colok) {
            __hip_bfloat16 tmp[4];
#pragma unroll
            for (int j = 0; j < 4; ++j) tmp[j] = __float2bfloat16(acc[i][j]);
            *(uint2*)&C[(size_t)m * N + n0 + tx * 4] = *(uint2*)tmp;
        }
        float ps = 0.f, pd = 0.f;
#pragma unroll
        for (int j = 0; j < 4; ++j) {
            ps += acc[i][j] * asv[j];
            pd += acc[i][j] * adv[j];
        }
        ps += __shfl_down(ps, 2, 4);
        ps += __shfl_down(ps, 1, 4);
        pd += __shfl_down(pd, 2, 4);
        pd += __shfl_down(pd, 1, 4);
        if (mok && colok && (tx & 3) == 0) {
            int hd = (n0 + tx * 4) >> 4;  // F=16
            es[(size_t)m * HHEADS + hd] = ps;
            ed[(size_t)m * HHEADS + hd] = pd;
        }
    }
}

// ---------------- MFMA split-bf16 GEMM + fused attn (layers 2/3) ----------------
template <int K, int NREAL, int NPAD, int F>
__global__ __launch_bounds__(256) void gemm_attn_mfma(
    const unsigned short* __restrict__ Ah, const unsigned short* __restrict__ Al,
    const unsigned short* __restrict__ Bh, const unsigned short* __restrict__ Bl,
    __hip_bfloat16* __restrict__ C, const float* __restrict__ as_,
    const float* __restrict__ ad_, float* __restrict__ es, float* __restrict__ ed, int M) {
    constexpr int NKT = K / 32;
    __shared__ unsigned short sAh[4096], sAl[4096], sBh[4096], sBl[4096];
    int tid = threadIdx.x;
    int lane = tid & 63, wave = tid >> 6;
    int wrow = wave >> 1, wcol = wave & 1;
    int quad = lane >> 4, c16 = lane & 15;
    int m0 = blockIdx.y * 128, n0 = blockIdx.x * 128;
    int bt16 = m0 >> 4, bn16 = n0 >> 4;

    f32x4 acc[4][4] = {};
    for (int kt = 0; kt < NKT; ++kt) {
#pragma unroll
        for (int rep = 0; rep < 2; ++rep) {
            int chunk = tid + rep * 256;
            int tile = chunk >> 6, e8 = chunk & 63;
            size_t aoff = ((size_t)((bt16 + tile) * NKT + kt) * 64 + e8) * 8;
            size_t boff = ((size_t)((bn16 + tile) * NKT + kt) * 64 + e8) * 8;
            *(uint4*)&sAh[chunk * 8] = *(const uint4*)&Ah[aoff];
            *(uint4*)&sAl[chunk * 8] = *(const uint4*)&Al[aoff];
            *(uint4*)&sBh[chunk * 8] = *(const uint4*)&Bh[boff];
            *(uint4*)&sBl[chunk * 8] = *(const uint4*)&Bl[boff];
        }
        __syncthreads();
        bf16x8 fah[4], fal[4], fbh[4], fbl[4];
#pragma unroll
        for (int i = 0; i < 4; ++i) {
            fah[i] = *(const bf16x8*)&sAh[(wrow * 4 + i) * 512 + lane * 8];
            fal[i] = *(const bf16x8*)&sAl[(wrow * 4 + i) * 512 + lane * 8];
            fbh[i] = *(const bf16x8*)&sBh[(wcol * 4 + i) * 512 + lane * 8];
            fbl[i] = *(const bf16x8*)&sBl[(wcol * 4 + i) * 512 + lane * 8];
        }
#pragma unroll
        for (int i = 0; i < 4; ++i)
#pragma unroll
            for (int j = 0; j < 4; ++j) {
                acc[i][j] = __builtin_amdgcn_mfma_f32_16x16x32_bf16(fah[i], fbh[j], acc[i][j],
                                                                    0, 0, 0);
                acc[i][j] = __builtin_amdgcn_mfma_f32_16x16x32_bf16(fal[i], fbh[j], acc[i][j],
                                                                    0, 0, 0);
                acc[i][j] = __builtin_amdgcn_mfma_f32_16x16x32_bf16(fah[i], fbl[j], acc[i][j],
                                                                    0, 0, 0);
            }
        __syncthreads();
    }

    float asv[4], adv[4];
#pragma unroll
    for (int j = 0; j < 4; ++j) {
        int col = n0 + wcol * 64 + j * 16 + c16;
        bool ok = col < NREAL;
        asv[j] = ok ? as_[col] : 0.f;
        adv[j] = ok ? ad_[col] : 0.f;
    }
#pragma unroll
    for (int i = 0; i < 4; ++i) {
#pragma unroll
        for (int r = 0; r < 4; ++r) {
            int m = m0 + wrow * 64 + i * 16 + quad * 4 + r;
            bool mok = m < M;
            if (mok) {
#pragma unroll
                for (int j = 0; j < 4; ++j) {
                    int col = n0 + wcol * 64 + j * 16 + c16;
                    if (col < NREAL) C[(size_t)m * NREAL + col] = __float2bfloat16(acc[i][j][r]);
                }
            }
            if (F == 64) {
                float ps = acc[i][0][r] * asv[0] + acc[i][1][r] * asv[1] +
                           acc[i][2][r] * asv[2] + acc[i][3][r] * asv[3];
                float pd = acc[i][0][r] * adv[0] + acc[i][1][r] * adv[1] +
                           acc[i][2][r] * adv[2] + acc[i][3][r] * adv[3];
#pragma unroll
                for (int off = 8; off > 0; off >>= 1) {
                    ps += __shfl_down(ps, off, 16);
                    pd += __shfl_down(pd, off, 16);
                }
                if (mok && c16 == 0) {
                    int hd = (n0 + wcol * 64) / 64;
                    es[(size_t)m * HHEADS + hd] = ps;
                    ed[(size_t)m * HHEADS + hd] = pd;
                }
            } else {  // F == 32: two heads per wave-column
                float psA = acc[i][0][r] * asv[0] + acc[i][1][r] * asv[1];
                float pdA = acc[i][0][r] * adv[0] + acc[i][1][r] * adv[1];
                float psB = acc[i][2][r] * asv[2] + acc[i][3][r] * asv[3];
                float pdB = acc[i][2][r] * adv[2] + acc[i][3][r] * adv[3];
#pragma unroll
                for (int off = 8; off > 0; off >>= 1) {
                    psA += __shfl_down(psA, off, 16);
                    pdA += __shfl_down(pdA, off, 16);
                    psB += __shfl_down(psB, off, 16);
                    pdB += __shfl_down(pdB, off, 16);
                }
                if (mok && c16 == 0) {
                    int colbase = n0 + wcol * 64;
                    if (colbase < NREAL) {
                        int hd = colbase / 32;
                        es[(size_t)m * HHEADS + hd] = psA;
                        ed[(size_t)m * HHEADS + hd] = pdA;
                        es[(size_t)m * HHEADS + hd + 1] = psB;
                        ed[(size_t)m * HHEADS + hd + 1] = pdB;
                    }
                }
            }
        }
    }
}

// ---------------- per-head global es max (softmax shift upper bound) ----------------
// gmax[hd] (fkey space, memset-0 = -inf identity). Sequential reads, LDS tree,
// 6 atomics per block. leaky(funkey(gmax)+ed) >= every row logit (monotone).
__global__ void es_gmax(const float* __restrict__ es, unsigned* __restrict__ gmax, int n) {
    __shared__ float sm[HHEADS][256];
    int t = threadIdx.x;
    float mx[HHEADS] = {-1e30f, -1e30f, -1e30f, -1e30f, -1e30f, -1e30f};
    for (int node = blockIdx.x * 256 + t; node < n; node += gridDim.x * 256) {
#pragma unroll
        for (int hd = 0; hd < HHEADS; ++hd)
            mx[hd] = fmaxf(mx[hd], es[(size_t)node * HHEADS + hd]);
    }
#pragma unroll
    for (int hd = 0; hd < HHEADS; ++hd) sm[hd][t] = mx[hd];
    __syncthreads();
    for (int s = 128; s > 0; s >>= 1) {
        if (t < s) {
#pragma unroll
            for (int hd = 0; hd < HHEADS; ++hd) sm[hd][t] = fmaxf(sm[hd][t], sm[hd][t + s]);
        }
        __syncthreads();
    }
    if (t < HHEADS) atomicMax(&gmax[t], fkey(sm[t][0]));
}

// ---------------- single-pass softmax-aggregate ----------------
// Thread owns CH channels. Shift m = leaky(gmax_es[hd] + ed) computed inline
// (upper bound on row logits: exps <= 1, ratios exact). Single gather pass.
// No block barrier (R11 lesson). PACK: split-bf16 MFMA A-operand planes.
template <int F, int CH, bool PACK>
__global__ __launch_bounds__(256) void aggregate_sp(
    const __hip_bfloat16* __restrict__ h, const float* __restrict__ es,
    const float* __restrict__ ed, const unsigned* __restrict__ gmax,
    const int* __restrict__ offsets, const int* __restrict__ ssrc,
    unsigned short* __restrict__ oh, unsigned short* __restrict__ ol,
    __hip_bfloat16* __restrict__ outb, int n) {
    constexpr int HF = HHEADS * F;
    constexpr int NQ = HF / CH;
    int tid = blockIdx.x * blockDim.x + threadIdx.x;
    if (tid >= n * NQ) return;
    int node = tid / NQ, q = tid % NQ;
    int c = q * CH, hd = c / F;
    int a = offsets[node], b = offsets[node + 1];
    float edv = ed[node * HHEADS + hd];
    float mv = funkey(gmax[hd]) + edv;
    float m = mv > 0.f ? mv : 0.2f * mv;  // leaky of bound = bound of leaky
    float l = 0.f;
    float acc[CH] = {};
    const unsigned short* hbase = (const unsigned short*)h + c;
    for (int j = a; j < b; ++j) {
        int s = ssrc[j];
        float v = es[s * HHEADS + hd] + edv;
        v = v > 0.f ? v : 0.2f * v;  // leaky relu 0.2
        float wgt = expf(v - m);
        l += wgt;
        const unsigned short* hp = hbase + (size_t)s * HF;
#pragma unroll
        for (int g2 = 0; g2 < CH / 8; ++g2) {
            uint4 hv = *(const uint4*)(hp + g2 * 8);
            acc[g2 * 8 + 0] += wgt * bfl(hv.x);
            acc[g2 * 8 + 1] += wgt * bfh(hv.x);
            acc[g2 * 8 + 2] += wgt * bfl(hv.y);
            acc[g2 * 8 + 3] += wgt * bfh(hv.y);
            acc[g2 * 8 + 4] += wgt * bfl(hv.z);
            acc[g2 * 8 + 5] += wgt * bfh(hv.z);
            acc[g2 * 8 + 6] += wgt * bfl(hv.w);
            acc[g2 * 8 + 7] += wgt * bfh(hv.w);
        }
    }
    float invd = 1.0f / (l + 1e-16f);
#pragma unroll
    for (int g2 = 0; g2 < CH / 8; ++g2) {
        float res[8];
#pragma unroll
        for (int k = 0; k < 8; ++k) {
            float v = acc[g2 * 8 + k] * invd;
            res[k] = v > 0.f ? v : (expf(v) - 1.0f);  // elu
        }
        int cc = c + g2 * 8;
        if (PACK) {
            constexpr int NKT = HF / 32;
            unsigned short th[8], tl[8];
#pragma unroll
            for (int k = 0; k < 8; ++k) {
                unsigned short hh = f2bf(res[k]);
                th[k] = hh;
                tl[k] = f2bf(res[k] - bf2f(hh));
            }
            int lq = (node & 15) | (((cc >> 3) & 3) << 4);
            size_t base = ((size_t)((node >> 4) * NKT + (cc >> 5)) * 64 + lq) * 8;
            *(uint4*)&oh[base] = *(uint4*)th;
            *(uint4*)&ol[base] = *(uint4*)tl;
        } else {
            __hip_bfloat16 tb[8];
#pragma unroll
            for (int k = 0; k < 8; ++k) tb[k] = __float2bfloat16(res[k]);
            *(uint4*)&outb[(size_t)node * HF + cc] = *(uint4*)tb;
        }
    }
}

// ---------------- pooling (bf16 input) + head ----------------
__global__ void pool_kernel(const __hip_bfloat16* __restrict__ out3, float* __restrict__ g,
                            int n) {
    int b = blockIdx.x, t = threadIdx.x;  // blockDim = 192
    int chunk = (n + gridDim.x - 1) / gridDim.x;
    int n0 = b * chunk, n1 = min(n, n0 + chunk);
    float a0 = 0.f, a1 = 0.f;
    const unsigned* p = (const unsigned*)out3;
    for (int node = n0; node < n1; ++node) {
        unsigned u = p[(size_t)node * 192 + t];
        a0 += bfl(u);
        a1 += bfh(u);
    }
    atomicAdd(&g[2 * t], a0);
    atomicAdd(&g[2 * t + 1], a1);
}

__global__ void final_kernel(const float* __restrict__ g, const float* __restrict__ Wd,
                             const float* __restrict__ bd, float* __restrict__ outp) {
    __shared__ float red[384];
    int t = threadIdx.x;  // blockDim = 384
    float v = g[t];
    red[t] = v * v;
    __syncthreads();
    for (int s = 192; s >= 3; s >>= 1) {
        if (t < s) red[t] += red[t + s];
        __syncthreads();
    }
    __shared__ float scale_s;
    if (t == 0) {
        float norm = sqrtf(red[0] + red[1] + red[2]);
        scale_s = 1.0f / fmaxf(norm, 1e-12f);
    }
    __syncthreads();
    float scale = scale_s;
    red[t] = v * scale * Wd[t];
    __syncthreads();
    for (int s = 192; s >= 3; s >>= 1) {
        if (t < s) red[t] += red[t + s];
        __syncthreads();
    }
    if (t == 0) outp[0] = red[0] + red[1] + red[2] + bd[0];
}

// ---------------- host side ----------------
extern "C" void kernel_launch(void* const* d_in, const int* in_sizes, int n_in, void* d_out,
                              int out_size, void* d_ws, size_t ws_size, hipStream_t stream) {
    const float* x = (const float*)d_in[0];
    const int* ei = (const int*)d_in[1];
    const float* W1 = (const float*)d_in[2];
    const float* a1s = (const float*)d_in[3];
    const float* a1d = (const float*)d_in[4];
    const float* W2 = (const float*)d_in[5];
    const float* a2s = (const float*)d_in[6];
    const float* a2d = (const float*)d_in[7];
    const float* W3 = (const float*)d_in[8];
    const float* a3s = (const float*)d_in[9];
    const float* a3d = (const float*)d_in[10];
    const float* Wd = (const float*)d_in[11];
    const float* bd = (const float*)d_in[12];
    float* outp = (float*)d_out;

    const int N = in_sizes[0] / 11;
    const int E = in_sizes[1] / 2;
    const int* src = ei;
    const int* dst = ei + E;

    const int NT16 = ((N + 127) / 128) * 8;  // padded 16-row tiles

    char* w = (char*)d_ws;
    size_t off = 0;
    auto A = [&](size_t bytes) {
        size_t o = off;
        off += (bytes + 255) & ~(size_t)255;
        return o;
    };
    __hip_bfloat16* bufH = (__hip_bfloat16*)(w + A((size_t)N * 384 * 2));  // h (bf16)
    __hip_bfloat16* bufO = (__hip_bfloat16*)(w + A((size_t)N * 384 * 2));  // layer3 out (bf16)
    unsigned short* apH = (unsigned short*)(w + A((size_t)NT16 * 6 * 512 * 2));  // A-pack hi
    unsigned short* apL = (unsigned short*)(w + A((size_t)NT16 * 6 * 512 * 2));  // A-pack lo
    unsigned short* b2H = (unsigned short*)(w + A((size_t)16 * 3 * 512 * 2));    // W2 pack
    unsigned short* b2L = (unsigned short*)(w + A((size_t)16 * 3 * 512 * 2));
    unsigned short* b3H = (unsigned short*)(w + A((size_t)24 * 6 * 512 * 2));    // W3 pack
    unsigned short* b3L = (unsigned short*)(w + A((size_t)24 * 6 * 512 * 2));
    float* es = (float*)(w + A((size_t)N * HHEADS * 4));
    float* ed = (float*)(w + A((size_t)N * HHEADS * 4));
    unsigned* gmax = (unsigned*)(w + A(256));
    float* wp = (float*)(w + A((size_t)11 * 96 * 4));  // layer-1 f32 repack
    int* count = (int*)(w + A((size_t)(N + 1) * 4));
    int* cursor = (int*)(w + A((size_t)(N + 1) * 4));
    int* offsets = (int*)(w + A((size_t)(N + 1) * 4));
    int* bsum = (int*)(w + A(64 * 4));
    int* ssrc = (int*)(w + A((size_t)E * 4));
    float* g = (float*)(w + A(384 * 4));

    // CSR build (by dst)
    hipMemsetAsync(count, 0, (size_t)N * 4, stream);
    hipMemsetAsync(cursor, 0, (size_t)N * 4, stream);
    hipMemsetAsync(g, 0, 384 * 4, stream);
    hist_kernel<<<(E + 255) / 256, 256, 0, stream>>>(dst, count, E);
    int nb = (N + 1023) / 1024;
    scan_block<<<nb, 1024, 0, stream>>>(count, offsets, bsum, N);
    scan_tops<<<1, 64, 0, stream>>>(bsum, nb);
    scan_add<<<nb, 1024, 0, stream>>>(offsets, bsum, N, E);
    scatter_kernel<<<(E + 255) / 256, 256, 0, stream>>>(src, dst, offsets, cursor, ssrc, E);

    // weight packs
    repack_w<<<(11 * 96 + 255) / 256, 256, 0, stream>>>(W1, wp, 11, 16);
    repack_w_mfma<<<(96 * 256 + 255) / 256, 256, 0, stream>>>(W2, b2H, b2L, 96, 32, 256);
    repack_w_mfma<<<(192 * 384 + 255) / 256, 256, 0, stream>>>(W3, b3H, b3L, 192, 64, 384);

    // zero A-pack pad tiles for both layouts (NKT=3 and 6)
    const int t16v = N / 16;
    const int padT = NT16 - t16v;
    hipMemsetAsync(apH + (size_t)t16v * 3 * 512, 0, (size_t)padT * 3 * 512 * 2, stream);
    hipMemsetAsync(apL + (size_t)t16v * 3 * 512, 0, (size_t)padT * 3 * 512 * 2, stream);
    hipMemsetAsync(apH + (size_t)t16v * 6 * 512, 0, (size_t)padT * 6 * 512 * 2, stream);
    hipMemsetAsync(apL + (size_t)t16v * 6 * 512, 0, (size_t)padT * 6 * 512 * 2, stream);

    // ---- layer 1 (FIN=11, F=16): gemm + fused attn terms ----
    {
        dim3 grid((96 + 63) / 64, (N + 63) / 64);
        gemm_small_attn<64, 64, 32><<<grid, 256, 0, stream>>>(x, wp, bufH, a1s, a1d, es, ed, N,
                                                              11, 96);
    }
    hipMemsetAsync(gmax, 0, HHEADS * 4, stream);
    es_gmax<<<128, 256, 0, stream>>>(es, gmax, N);
    {
        long total = (long)N * (96 / 8);
        aggregate_sp<16, 8, true><<<(total + 255) / 256, 256, 0, stream>>>(
            bufH, es, ed, gmax, offsets, ssrc, apH, apL, nullptr, N);
    }

    // ---- layer 2 (K=96, N=192 pad 256, F=32) ----
    {
        dim3 grid(256 / 128, (N + 127) / 128);
        gemm_attn_mfma<96, 192, 256, 32><<<grid, 256, 0, stream>>>(apH, apL, b2H, b2L, bufH,
                                                                   a2s, a2d, es, ed, N);
    }
    hipMemsetAsync(gmax, 0, HHEADS * 4, stream);
    es_gmax<<<128, 256, 0, stream>>>(es, gmax, N);
    {
        long total = (long)N * (192 / 8);
        aggregate_sp<32, 8, true><<<(total + 255) / 256, 256, 0, stream>>>(
            bufH, es, ed, gmax, offsets, ssrc, apH, apL, nullptr, N);
    }

    // ---- layer 3 (K=192, N=384, F=64) ----
    {
        dim3 grid(384 / 128, (N + 127) / 128);
        gemm_attn_mfma<192, 384, 384, 64><<<grid, 256, 0, stream>>>(apH, apL, b3H, b3L, bufH,
                                                                    a3s, a3d, es, ed, N);
    }
    hipMemsetAsync(gmax, 0, HHEADS * 4, stream);
    es_gmax<<<128, 256, 0, stream>>>(es, gmax, N);
    {
        long total = (long)N * (384 / 16);
        aggregate_sp<64, 16, false><<<(total + 255) / 256, 256, 0, stream>>>(
            bufH, es, ed, gmax, offsets, ssrc, nullptr, nullptr, bufO, N);
    }

    // sum-pool (bf16 in) -> normalize -> dense
    pool_kernel<<<256, 192, 0, stream>>>(bufO, g, N);
    final_kernel<<<1, 384, 0, stream>>>(g, Wd, bd, outp);
}

// Round 17
// 540.946 us; speedup vs baseline: 1.0714x; 1.0597x over previous
//
#include <hip/hip_runtime.h>
#include <hip/hip_bf16.h>

// GAT 3-layer: N=50000 nodes, E=800000 edges, H=6 heads.
// R1-R10: tiled/MFMA-split-bf16 GEMMs (operands pre-packed in fragment layout),
//         CSR dst-centric fused softmax+aggregate, bf16 h. absmax=0.
// R11-R16 aggregate experiments (A/B evidence):
//   - online-rescale C8, no helpers (R12): best for L1/L2 (latency-bound).
//   - single-pass C16 + global-es-max bound (R16): best for L3 (116->103us).
//   - block barriers after gather loops, per-head threads, rowmax kernels: all
//     regressed. Aggregate is gather-path bound (~6 TB/s effective service).
// R17: consolidation: R12 aggregates for L1/L2, R16 single-pass for L3, all
//      small memsets collapsed into one zero_misc dispatch (~30 -> ~18 total).

#define HHEADS 6

typedef __attribute__((ext_vector_type(8))) short bf16x8;   // 8 bf16 = 4 VGPR
typedef __attribute__((ext_vector_type(4))) float f32x4;    // mfma C/D

__device__ __forceinline__ float bfl(unsigned u) { return __uint_as_float(u << 16); }
__device__ __forceinline__ float bfh(unsigned u) { return __uint_as_float(u & 0xffff0000u); }
__device__ __forceinline__ unsigned short f2bf(float v) {  // RNE f32->bf16
    unsigned u = __float_as_uint(v);
    return (unsigned short)((u + 0x7fffu + ((u >> 16) & 1u)) >> 16);
}
__device__ __forceinline__ float bf2f(unsigned short h) {
    return __uint_as_float((unsigned)h << 16);
}
// monotone float<->uint for atomicMax on floats (memset-0 = -inf identity)
__device__ __forceinline__ unsigned fkey(float f) {
    unsigned u = __float_as_uint(f);
    return (u >> 31) ? ~u : (u | 0x80000000u);
}
__device__ __forceinline__ float funkey(unsigned k) {
    return (k >> 31) ? __uint_as_float(k & 0x7fffffffu) : __uint_as_float(~k);
}

// ---------------- one-shot zero of all small scratch ----------------
__global__ void zero_misc(int* __restrict__ count, int* __restrict__ cursor,
                          float* __restrict__ g, unsigned* __restrict__ gmax,
                          unsigned short* __restrict__ apH, unsigned short* __restrict__ apL,
                          long pad3_off, long pad3_cnt, long pad6_off, long pad6_cnt, int n) {
    long i = (long)blockIdx.x * blockDim.x + threadIdx.x;
    long stride = (long)gridDim.x * blockDim.x;
    for (long j = i; j < n; j += stride) {
        count[j] = 0;
        cursor[j] = 0;
    }
    if (i < 384) g[i] = 0.f;
    if (i < HHEADS) gmax[i] = 0u;
    for (long j = i; j < pad3_cnt; j += stride) {
        apH[pad3_off + j] = 0;
        apL[pad3_off + j] = 0;
    }
    for (long j = i; j < pad6_cnt; j += stride) {
        apH[pad6_off + j] = 0;
        apL[pad6_off + j] = 0;
    }
}

// ---------------- CSR build ----------------
__global__ void hist_kernel(const int* __restrict__ dst, int* __restrict__ count, int E) {
    int e = blockIdx.x * blockDim.x + threadIdx.x;
    if (e >= E) return;
    atomicAdd(&count[dst[e]], 1);
}

__global__ void scan_block(const int* __restrict__ count, int* __restrict__ offsets,
                           int* __restrict__ bsum, int n) {
    __shared__ int s[1024];
    int i = blockIdx.x * 1024 + threadIdx.x;
    int v = (i < n) ? count[i] : 0;
    s[threadIdx.x] = v;
    __syncthreads();
    for (int off = 1; off < 1024; off <<= 1) {
        int t = (threadIdx.x >= (unsigned)off) ? s[threadIdx.x - off] : 0;
        __syncthreads();
        s[threadIdx.x] += t;
        __syncthreads();
    }
    if (i < n) offsets[i] = s[threadIdx.x] - v;
    if (threadIdx.x == 1023) bsum[blockIdx.x] = s[1023];
}

__global__ void scan_tops(int* __restrict__ bsum, int nb) {
    __shared__ int s[64];
    int t = threadIdx.x;
    int v = (t < nb) ? bsum[t] : 0;
    s[t] = v;
    __syncthreads();
    for (int off = 1; off < 64; off <<= 1) {
        int tmp = (t >= off) ? s[t - off] : 0;
        __syncthreads();
        s[t] += tmp;
        __syncthreads();
    }
    if (t < nb) bsum[t] = s[t] - v;
}

__global__ void scan_add(int* __restrict__ offsets, const int* __restrict__ bsum, int n,
                         int total) {
    int i = blockIdx.x * 1024 + threadIdx.x;
    if (i < n) offsets[i] += bsum[blockIdx.x];
    if (i == 0) offsets[n] = total;
}

__global__ void scatter_kernel(const int* __restrict__ src, const int* __restrict__ dst,
                               const int* __restrict__ offsets, int* __restrict__ cursor,
                               int* __restrict__ ssrc, int E) {
    int e = blockIdx.x * blockDim.x + threadIdx.x;
    if (e >= E) return;
    int d = dst[e];
    int pos = offsets[d] + atomicAdd(&cursor[d], 1);
    ssrc[pos] = src[e];
}

// ---------------- weight repacks ----------------
__global__ void repack_w(const float* __restrict__ W, float* __restrict__ Wp, int FIN, int F) {
    int HF = HHEADS * F;
    int i = blockIdx.x * blockDim.x + threadIdx.x;
    if (i >= FIN * HF) return;
    int k = i / HF, c = i % HF;
    int hd = c / F, f = c % F;
    Wp[i] = W[(hd * FIN + k) * F + f];
}

// split-bf16 pack in MFMA B-fragment layout (B^T: lane n=..&15, k contiguous)
__global__ void repack_w_mfma(const float* __restrict__ W, unsigned short* __restrict__ bh,
                              unsigned short* __restrict__ bl, int FIN, int F, int NPAD) {
    int i = blockIdx.x * blockDim.x + threadIdx.x;
    if (i >= FIN * NPAD) return;
    int k = i / NPAD, n = i % NPAD;
    int NKT = FIN / 32;
    int HF = HHEADS * F;
    float w = 0.f;
    if (n < HF) {
        int hd = n / F, f = n % F;
        w = W[(hd * FIN + k) * F + f];
    }
    unsigned short h = f2bf(w);
    unsigned short l = f2bf(w - bf2f(h));
    size_t e = ((size_t)((n >> 4) * NKT + (k >> 5)) * 64 + ((n & 15) | (((k >> 3) & 3) << 4))) * 8 +
               (k & 7);
    bh[e] = h;
    bl[e] = l;
}

// ---------------- small GEMM + fused attn (layer 1, K=11, F=16) ----------------
template <int BM, int BN, int BK>
__global__ __launch_bounds__(256) void gemm_small_attn(const float* __restrict__ A,
                                                       const float* __restrict__ B,
                                                       __hip_bfloat16* __restrict__ C,
                                                       const float* __restrict__ as_,
                                                       const float* __restrict__ ad_,
                                                       float* __restrict__ es,
                                                       float* __restrict__ ed, int M, int K,
                                                       int N) {
    __shared__ float As[BK][BM + 4];
    __shared__ float Bs[BK][BN];
    int tid = threadIdx.x;
    int tx = tid % 16, ty = tid / 16;
    int m0 = blockIdx.y * BM, n0 = blockIdx.x * BN;
    float acc[4][4] = {};
    for (int kk0 = 0; kk0 < K; kk0 += BK) {
#pragma unroll
        for (int i = 0; i < (BM * BK) / 256; ++i) {
            int idx = tid + i * 256;
            int m = idx / BK, k = idx % BK;
            float v = 0.f;
            if (m0 + m < M && kk0 + k < K) v = A[(size_t)(m0 + m) * K + kk0 + k];
            As[k][m] = v;
        }
#pragma unroll
        for (int i = 0; i < (BK * BN) / 1024; ++i) {
            int idx = tid + i * 256;
            int k = idx / (BN / 4), n4 = idx % (BN / 4);
            float4 v = make_float4(0.f, 0.f, 0.f, 0.f);
            if (kk0 + k < K && n0 + n4 * 4 < N)
                v = *(const float4*)&B[(size_t)(kk0 + k) * N + n0 + n4 * 4];
            *(float4*)&Bs[k][n4 * 4] = v;
        }
        __syncthreads();
#pragma unroll
        for (int k = 0; k < BK; ++k) {
            float4 av = *(const float4*)&As[k][ty * 4];
            float4 bv = *(const float4*)&Bs[k][tx * 4];
            float a[4] = {av.x, av.y, av.z, av.w};
            float b[4] = {bv.x, bv.y, bv.z, bv.w};
#pragma unroll
            for (int i = 0; i < 4; ++i)
#pragma unroll
                for (int j = 0; j < 4; ++j) acc[i][j] += a[i] * b[j];
        }
        __syncthreads();
    }
    bool colok = (n0 + tx * 4) < N;
    float asv[4], adv[4];
#pragma unroll
    for (int j = 0; j < 4; ++j) {
        int col = n0 + tx * 4 + j;
        asv[j] = (col < N) ? as_[col] : 0.f;
        adv[j] = (col < N) ? ad_[col] : 0.f;
    }
#pragma unroll
    for (int i = 0; i < 4; ++i) {
        int m = m0 + ty * 4 + i;
        bool mok = m < M;
        if (mok && colok) {
            __hip_bfloat16 tmp[4];
#pragma unroll
            for (int j = 0; j < 4; ++j) tmp[j] = __float2bfloat16(acc[i][j]);
            *(uint2*)&C[(size_t)m * N + n0 + tx * 4] = *(uint2*)tmp;
        }
        float ps = 0.f, pd = 0.f;
#pragma unroll
        for (int j = 0; j < 4; ++j) {
            ps += acc[i][j] * asv[j];
            pd += acc[i][j] * adv[j];
        }
        ps += __shfl_down(ps, 2, 4);
        ps += __shfl_down(ps, 1, 4);
        pd += __shfl_down(pd, 2, 4);
        pd += __shfl_down(pd, 1, 4);
        if (mok && colok && (tx & 3) == 0) {
            int hd = (n0 + tx * 4) >> 4;  // F=16
            es[(size_t)m * HHEADS + hd] = ps;
            ed[(size_t)m * HHEADS + hd] = pd;
        }
    }
}

// ---------------- MFMA split-bf16 GEMM + fused attn (layers 2/3) ----------------
template <int K, int NREAL, int NPAD, int F>
__global__ __launch_bounds__(256) void gemm_attn_mfma(
    const unsigned short* __restrict__ Ah, const unsigned short* __restrict__ Al,
    const unsigned short* __restrict__ Bh, const unsigned short* __restrict__ Bl,
    __hip_bfloat16* __restrict__ C, const float* __restrict__ as_,
    const float* __restrict__ ad_, float* __restrict__ es, float* __restrict__ ed, int M) {
    constexpr int NKT = K / 32;
    __shared__ unsigned short sAh[4096], sAl[4096], sBh[4096], sBl[4096];
    int tid = threadIdx.x;
    int lane = tid & 63, wave = tid >> 6;
    int wrow = wave >> 1, wcol = wave & 1;
    int quad = lane >> 4, c16 = lane & 15;
    int m0 = blockIdx.y * 128, n0 = blockIdx.x * 128;
    int bt16 = m0 >> 4, bn16 = n0 >> 4;

    f32x4 acc[4][4] = {};
    for (int kt = 0; kt < NKT; ++kt) {
#pragma unroll
        for (int rep = 0; rep < 2; ++rep) {
            int chunk = tid + rep * 256;
            int tile = chunk >> 6, e8 = chunk & 63;
            size_t aoff = ((size_t)((bt16 + tile) * NKT + kt) * 64 + e8) * 8;
            size_t boff = ((size_t)((bn16 + tile) * NKT + kt) * 64 + e8) * 8;
            *(uint4*)&sAh[chunk * 8] = *(const uint4*)&Ah[aoff];
            *(uint4*)&sAl[chunk * 8] = *(const uint4*)&Al[aoff];
            *(uint4*)&sBh[chunk * 8] = *(const uint4*)&Bh[boff];
            *(uint4*)&sBl[chunk * 8] = *(const uint4*)&Bl[boff];
        }
        __syncthreads();
        bf16x8 fah[4], fal[4], fbh[4], fbl[4];
#pragma unroll
        for (int i = 0; i < 4; ++i) {
            fah[i] = *(const bf16x8*)&sAh[(wrow * 4 + i) * 512 + lane * 8];
            fal[i] = *(const bf16x8*)&sAl[(wrow * 4 + i) * 512 + lane * 8];
            fbh[i] = *(const bf16x8*)&sBh[(wcol * 4 + i) * 512 + lane * 8];
            fbl[i] = *(const bf16x8*)&sBl[(wcol * 4 + i) * 512 + lane * 8];
        }
#pragma unroll
        for (int i = 0; i < 4; ++i)
#pragma unroll
            for (int j = 0; j < 4; ++j) {
                acc[i][j] = __builtin_amdgcn_mfma_f32_16x16x32_bf16(fah[i], fbh[j], acc[i][j],
                                                                    0, 0, 0);
                acc[i][j] = __builtin_amdgcn_mfma_f32_16x16x32_bf16(fal[i], fbh[j], acc[i][j],
                                                                    0, 0, 0);
                acc[i][j] = __builtin_amdgcn_mfma_f32_16x16x32_bf16(fah[i], fbl[j], acc[i][j],
                                                                    0, 0, 0);
            }
        __syncthreads();
    }

    float asv[4], adv[4];
#pragma unroll
    for (int j = 0; j < 4; ++j) {
        int col = n0 + wcol * 64 + j * 16 + c16;
        bool ok = col < NREAL;
        asv[j] = ok ? as_[col] : 0.f;
        adv[j] = ok ? ad_[col] : 0.f;
    }
#pragma unroll
    for (int i = 0; i < 4; ++i) {
#pragma unroll
        for (int r = 0; r < 4; ++r) {
            int m = m0 + wrow * 64 + i * 16 + quad * 4 + r;
            bool mok = m < M;
            if (mok) {
#pragma unroll
                for (int j = 0; j < 4; ++j) {
                    int col = n0 + wcol * 64 + j * 16 + c16;
                    if (col < NREAL) C[(size_t)m * NREAL + col] = __float2bfloat16(acc[i][j][r]);
                }
            }
            if (F == 64) {
                float ps = acc[i][0][r] * asv[0] + acc[i][1][r] * asv[1] +
                           acc[i][2][r] * asv[2] + acc[i][3][r] * asv[3];
                float pd = acc[i][0][r] * adv[0] + acc[i][1][r] * adv[1] +
                           acc[i][2][r] * adv[2] + acc[i][3][r] * adv[3];
#pragma unroll
                for (int off = 8; off > 0; off >>= 1) {
                    ps += __shfl_down(ps, off, 16);
                    pd += __shfl_down(pd, off, 16);
                }
                if (mok && c16 == 0) {
                    int hd = (n0 + wcol * 64) / 64;
                    es[(size_t)m * HHEADS + hd] = ps;
                    ed[(size_t)m * HHEADS + hd] = pd;
                }
            } else {  // F == 32: two heads per wave-column
                float psA = acc[i][0][r] * asv[0] + acc[i][1][r] * asv[1];
                float pdA = acc[i][0][r] * adv[0] + acc[i][1][r] * adv[1];
                float psB = acc[i][2][r] * asv[2] + acc[i][3][r] * asv[3];
                float pdB = acc[i][2][r] * adv[2] + acc[i][3][r] * adv[3];
#pragma unroll
                for (int off = 8; off > 0; off >>= 1) {
                    psA += __shfl_down(psA, off, 16);
                    pdA += __shfl_down(pdA, off, 16);
                    psB += __shfl_down(psB, off, 16);
                    pdB += __shfl_down(pdB, off, 16);
                }
                if (mok && c16 == 0) {
                    int colbase = n0 + wcol * 64;
                    if (colbase < NREAL) {
                        int hd = colbase / 32;
                        es[(size_t)m * HHEADS + hd] = psA;
                        ed[(size_t)m * HHEADS + hd] = pdA;
                        es[(size_t)m * HHEADS + hd + 1] = psB;
                        ed[(size_t)m * HHEADS + hd + 1] = pdB;
                    }
                }
            }
        }
    }
}

// ---------------- online-rescale softmax-aggregate (layers 1/2) ----------------
// Thread per (node, 8ch); flash-style online max/sum; zero helper kernels.
// No block barrier (R11 lesson). Emits split-bf16 MFMA A-operand planes.
template <int F>
__global__ __launch_bounds__(256) void aggregate_fused(
    const __hip_bfloat16* __restrict__ h, const float* __restrict__ es,
    const float* __restrict__ ed, const int* __restrict__ offsets,
    const int* __restrict__ ssrc, unsigned short* __restrict__ oh,
    unsigned short* __restrict__ ol, int n) {
    constexpr int HF = HHEADS * F;
    constexpr int C8 = HF / 8;
    int tid = blockIdx.x * blockDim.x + threadIdx.x;
    if (tid >= n * C8) return;
    int node = tid / C8, q = tid % C8;
    int c = q * 8, hd = c / F;
    int a = offsets[node], b = offsets[node + 1];
    float edv = ed[node * HHEADS + hd];
    float m = -1e30f, l = 0.f;
    float acc[8] = {};
    for (int j = a; j < b; ++j) {
        int s = ssrc[j];
        float v = es[s * HHEADS + hd] + edv;
        v = v > 0.f ? v : 0.2f * v;  // leaky relu 0.2
        float mn = fmaxf(m, v);
        float r = expf(m - mn);
        float wgt = expf(v - mn);
        uint4 hv = *(const uint4*)&h[(size_t)s * HF + c];
        l = l * r + wgt;
        acc[0] = acc[0] * r + wgt * bfl(hv.x);
        acc[1] = acc[1] * r + wgt * bfh(hv.x);
        acc[2] = acc[2] * r + wgt * bfl(hv.y);
        acc[3] = acc[3] * r + wgt * bfh(hv.y);
        acc[4] = acc[4] * r + wgt * bfl(hv.z);
        acc[5] = acc[5] * r + wgt * bfh(hv.z);
        acc[6] = acc[6] * r + wgt * bfl(hv.w);
        acc[7] = acc[7] * r + wgt * bfh(hv.w);
        m = mn;
    }
    float invd = 1.0f / (l + 1e-16f);
    float res[8];
#pragma unroll
    for (int k = 0; k < 8; ++k) {
        float v = acc[k] * invd;
        res[k] = v > 0.f ? v : (expf(v) - 1.0f);  // elu
    }
    constexpr int NKT = HF / 32;
    unsigned short th[8], tl[8];
#pragma unroll
    for (int k = 0; k < 8; ++k) {
        unsigned short hh = f2bf(res[k]);
        th[k] = hh;
        tl[k] = f2bf(res[k] - bf2f(hh));
    }
    int lq = (node & 15) | (((c >> 3) & 3) << 4);
    size_t base = ((size_t)((node >> 4) * NKT + (c >> 5)) * 64 + lq) * 8;
    *(uint4*)&oh[base] = *(uint4*)th;
    *(uint4*)&ol[base] = *(uint4*)tl;
}

// ---------------- per-head global es max (softmax shift upper bound) ----------------
__global__ void es_gmax(const float* __restrict__ es, unsigned* __restrict__ gmax, int n) {
    __shared__ float sm[HHEADS][256];
    int t = threadIdx.x;
    float mx[HHEADS] = {-1e30f, -1e30f, -1e30f, -1e30f, -1e30f, -1e30f};
    for (int node = blockIdx.x * 256 + t; node < n; node += gridDim.x * 256) {
#pragma unroll
        for (int hd = 0; hd < HHEADS; ++hd)
            mx[hd] = fmaxf(mx[hd], es[(size_t)node * HHEADS + hd]);
    }
#pragma unroll
    for (int hd = 0; hd < HHEADS; ++hd) sm[hd][t] = mx[hd];
    __syncthreads();
    for (int s = 128; s > 0; s >>= 1) {
        if (t < s) {
#pragma unroll
            for (int hd = 0; hd < HHEADS; ++hd) sm[hd][t] = fmaxf(sm[hd][t], sm[hd][t + s]);
        }
        __syncthreads();
    }
    if (t < HHEADS) atomicMax(&gmax[t], fkey(sm[t][0]));
}

// ---------------- single-pass softmax-aggregate (layer 3) ----------------
// Thread per (node, 16ch); shift m = leaky(gmax_es[hd]+ed) is an upper bound
// on row logits (leaky monotone); ratios exact. bf16 row-major out.
template <int F, int CH>
__global__ __launch_bounds__(256) void aggregate_sp(
    const __hip_bfloat16* __restrict__ h, const float* __restrict__ es,
    const float* __restrict__ ed, const unsigned* __restrict__ gmax,
    const int* __restrict__ offsets, const int* __restrict__ ssrc,
    __hip_bfloat16* __restrict__ outb, int n) {
    constexpr int HF = HHEADS * F;
    constexpr int NQ = HF / CH;
    int tid = blockIdx.x * blockDim.x + threadIdx.x;
    if (tid >= n * NQ) return;
    int node = tid / NQ, q = tid % NQ;
    int c = q * CH, hd = c / F;
    int a = offsets[node], b = offsets[node + 1];
    float edv = ed[node * HHEADS + hd];
    float mv = funkey(gmax[hd]) + edv;
    float m = mv > 0.f ? mv : 0.2f * mv;
    float l = 0.f;
    float acc[CH] = {};
    const unsigned short* hbase = (const unsigned short*)h + c;
    for (int j = a; j < b; ++j) {
        int s = ssrc[j];
        float v = es[s * HHEADS + hd] + edv;
        v = v > 0.f ? v : 0.2f * v;  // leaky relu 0.2
        float wgt = expf(v - m);
        l += wgt;
        const unsigned short* hp = hbase + (size_t)s * HF;
#pragma unroll
        for (int g2 = 0; g2 < CH / 8; ++g2) {
            uint4 hv = *(const uint4*)(hp + g2 * 8);
            acc[g2 * 8 + 0] += wgt * bfl(hv.x);
            acc[g2 * 8 + 1] += wgt * bfh(hv.x);
            acc[g2 * 8 + 2] += wgt * bfl(hv.y);
            acc[g2 * 8 + 3] += wgt * bfh(hv.y);
            acc[g2 * 8 + 4] += wgt * bfl(hv.z);
            acc[g2 * 8 + 5] += wgt * bfh(hv.z);
            acc[g2 * 8 + 6] += wgt * bfl(hv.w);
            acc[g2 * 8 + 7] += wgt * bfh(hv.w);
        }
    }
    float invd = 1.0f / (l + 1e-16f);
#pragma unroll
    for (int g2 = 0; g2 < CH / 8; ++g2) {
        __hip_bfloat16 tb[8];
#pragma unroll
        for (int k = 0; k < 8; ++k) {
            float v = acc[g2 * 8 + k] * invd;
            v = v > 0.f ? v : (expf(v) - 1.0f);  // elu
            tb[k] = __float2bfloat16(v);
        }
        *(uint4*)&outb[(size_t)node * HF + c + g2 * 8] = *(uint4*)tb;
    }
}

// ---------------- pooling (bf16 input) + head ----------------
__global__ void pool_kernel(const __hip_bfloat16* __restrict__ out3, float* __restrict__ g,
                            int n) {
    int b = blockIdx.x, t = threadIdx.x;  // blockDim = 192
    int chunk = (n + gridDim.x - 1) / gridDim.x;
    int n0 = b * chunk, n1 = min(n, n0 + chunk);
    float a0 = 0.f, a1 = 0.f;
    const unsigned* p = (const unsigned*)out3;
    for (int node = n0; node < n1; ++node) {
        unsigned u = p[(size_t)node * 192 + t];
        a0 += bfl(u);
        a1 += bfh(u);
    }
    atomicAdd(&g[2 * t], a0);
    atomicAdd(&g[2 * t + 1], a1);
}

__global__ void final_kernel(const float* __restrict__ g, const float* __restrict__ Wd,
                             const float* __restrict__ bd, float* __restrict__ outp) {
    __shared__ float red[384];
    int t = threadIdx.x;  // blockDim = 384
    float v = g[t];
    red[t] = v * v;
    __syncthreads();
    for (int s = 192; s >= 3; s >>= 1) {
        if (t < s) red[t] += red[t + s];
        __syncthreads();
    }
    __shared__ float scale_s;
    if (t == 0) {
        float norm = sqrtf(red[0] + red[1] + red[2]);
        scale_s = 1.0f / fmaxf(norm, 1e-12f);
    }
    __syncthreads();
    float scale = scale_s;
    red[t] = v * scale * Wd[t];
    __syncthreads();
    for (int s = 192; s >= 3; s >>= 1) {
        if (t < s) red[t] += red[t + s];
        __syncthreads();
    }
    if (t == 0) outp[0] = red[0] + red[1] + red[2] + bd[0];
}

// ---------------- host side ----------------
extern "C" void kernel_launch(void* const* d_in, const int* in_sizes, int n_in, void* d_out,
                              int out_size, void* d_ws, size_t ws_size, hipStream_t stream) {
    const float* x = (const float*)d_in[0];
    const int* ei = (const int*)d_in[1];
    const float* W1 = (const float*)d_in[2];
    const float* a1s = (const float*)d_in[3];
    const float* a1d = (const float*)d_in[4];
    const float* W2 = (const float*)d_in[5];
    const float* a2s = (const float*)d_in[6];
    const float* a2d = (const float*)d_in[7];
    const float* W3 = (const float*)d_in[8];
    const float* a3s = (const float*)d_in[9];
    const float* a3d = (const float*)d_in[10];
    const float* Wd = (const float*)d_in[11];
    const float* bd = (const float*)d_in[12];
    float* outp = (float*)d_out;

    const int N = in_sizes[0] / 11;
    const int E = in_sizes[1] / 2;
    const int* src = ei;
    const int* dst = ei + E;

    const int NT16 = ((N + 127) / 128) * 8;  // padded 16-row tiles

    char* w = (char*)d_ws;
    size_t off = 0;
    auto A = [&](size_t bytes) {
        size_t o = off;
        off += (bytes + 255) & ~(size_t)255;
        return o;
    };
    __hip_bfloat16* bufH = (__hip_bfloat16*)(w + A((size_t)N * 384 * 2));  // h (bf16)
    __hip_bfloat16* bufO = (__hip_bfloat16*)(w + A((size_t)N * 384 * 2));  // layer3 out (bf16)
    unsigned short* apH = (unsigned short*)(w + A((size_t)NT16 * 6 * 512 * 2));  // A-pack hi
    unsigned short* apL = (unsigned short*)(w + A((size_t)NT16 * 6 * 512 * 2));  // A-pack lo
    unsigned short* b2H = (unsigned short*)(w + A((size_t)16 * 3 * 512 * 2));    // W2 pack
    unsigned short* b2L = (unsigned short*)(w + A((size_t)16 * 3 * 512 * 2));
    unsigned short* b3H = (unsigned short*)(w + A((size_t)24 * 6 * 512 * 2));    // W3 pack
    unsigned short* b3L = (unsigned short*)(w + A((size_t)24 * 6 * 512 * 2));
    float* es = (float*)(w + A((size_t)N * HHEADS * 4));
    float* ed = (float*)(w + A((size_t)N * HHEADS * 4));
    unsigned* gmax = (unsigned*)(w + A(256));
    float* wp = (float*)(w + A((size_t)11 * 96 * 4));  // layer-1 f32 repack
    int* count = (int*)(w + A((size_t)(N + 1) * 4));
    int* cursor = (int*)(w + A((size_t)(N + 1) * 4));
    int* offsets = (int*)(w + A((size_t)(N + 1) * 4));
    int* bsum = (int*)(w + A(64 * 4));
    int* ssrc = (int*)(w + A((size_t)E * 4));
    float* g = (float*)(w + A(384 * 4));

    // one-shot zero of all small scratch (count, cursor, g, gmax, A-pack pads)
    const long t16v = N / 16;
    const long padT = NT16 - t16v;
    zero_misc<<<(N + 255) / 256, 256, 0, stream>>>(count, cursor, g, gmax, apH, apL,
                                                   t16v * 3 * 512, padT * 3 * 512,
                                                   t16v * 6 * 512, padT * 6 * 512, N);

    // CSR build (by dst)
    hist_kernel<<<(E + 255) / 256, 256, 0, stream>>>(dst, count, E);
    int nb = (N + 1023) / 1024;
    scan_block<<<nb, 1024, 0, stream>>>(count, offsets, bsum, N);
    scan_tops<<<1, 64, 0, stream>>>(bsum, nb);
    scan_add<<<nb, 1024, 0, stream>>>(offsets, bsum, N, E);
    scatter_kernel<<<(E + 255) / 256, 256, 0, stream>>>(src, dst, offsets, cursor, ssrc, E);

    // weight packs
    repack_w<<<(11 * 96 + 255) / 256, 256, 0, stream>>>(W1, wp, 11, 16);
    repack_w_mfma<<<(96 * 256 + 255) / 256, 256, 0, stream>>>(W2, b2H, b2L, 96, 32, 256);
    repack_w_mfma<<<(192 * 384 + 255) / 256, 256, 0, stream>>>(W3, b3H, b3L, 192, 64, 384);

    // ---- layer 1 (FIN=11, F=16): gemm + fused attn terms ----
    {
        dim3 grid((96 + 63) / 64, (N + 63) / 64);
        gemm_small_attn<64, 64, 32><<<grid, 256, 0, stream>>>(x, wp, bufH, a1s, a1d, es, ed, N,
                                                              11, 96);
    }
    {
        long total = (long)N * (96 / 8);
        aggregate_fused<16><<<(total + 255) / 256, 256, 0, stream>>>(bufH, es, ed, offsets,
                                                                     ssrc, apH, apL, N);
    }

    // ---- layer 2 (K=96, N=192 pad 256, F=32) ----
    {
        dim3 grid(256 / 128, (N + 127) / 128);
        gemm_attn_mfma<96, 192, 256, 32><<<grid, 256, 0, stream>>>(apH, apL, b2H, b2L, bufH,
                                                                   a2s, a2d, es, ed, N);
    }
    {
        long total = (long)N * (192 / 8);
        aggregate_fused<32><<<(total + 255) / 256, 256, 0, stream>>>(bufH, es, ed, offsets,
                                                                     ssrc, apH, apL, N);
    }

    // ---- layer 3 (K=192, N=384, F=64): single-pass agg w/ global-max shift ----
    {
        dim3 grid(384 / 128, (N + 127) / 128);
        gemm_attn_mfma<192, 384, 384, 64><<<grid, 256, 0, stream>>>(apH, apL, b3H, b3L, bufH,
                                                                    a3s, a3d, es, ed, N);
    }
    es_gmax<<<128, 256, 0, stream>>>(es, gmax, N);
    {
        long total = (long)N * (384 / 16);
        aggregate_sp<64, 16><<<(total + 255) / 256, 256, 0, stream>>>(bufH, es, ed, gmax,
                                                                      offsets, ssrc, bufO, N);
    }

    // sum-pool (bf16 in) -> normalize -> dense
    pool_kernel<<<256, 192, 0, stream>>>(bufO, g, N);
    final_kernel<<<1, 384, 0, stream>>>(g, Wd, bd, outp);
}